// Round 4
// baseline (659.884 us; speedup 1.0000x reference)
//
#include <hip/hip_runtime.h>
#include <hip/hip_bf16.h>

typedef __attribute__((ext_vector_type(8))) short short8;
typedef __attribute__((ext_vector_type(4))) float f32x4;

#define DEVI static __device__ __forceinline__

DEVI ushort f2bf(float f) {
  union { __hip_bfloat16 h; ushort u; } c; c.h = __float2bfloat16(f); return c.u;
}
DEVI float bf2f(ushort u) {
  union { __hip_bfloat16 h; ushort u; } c; c.u = u; return __bfloat162float(c.h);
}

// async global->LDS, 16B per lane. LDS dest must be wave-uniform base + lane*16.
DEVI void gload16(const ushort* g, ushort* l) {
  __builtin_amdgcn_global_load_lds(
      (const __attribute__((address_space(1))) void*)g,
      (__attribute__((address_space(3))) void*)l, 16, 0, 0);
}

// block-wide (256 threads) reduction of two values
DEVI void blk_reduce2(float& a, float& b) {
  #pragma unroll
  for (int m = 1; m < 64; m <<= 1) {
    a += __shfl_xor(a, m);
    b += __shfl_xor(b, m);
  }
  __shared__ float sc[8];
  int tid = threadIdx.x, w = tid >> 6;
  if ((tid & 63) == 0) { sc[w * 2] = a; sc[w * 2 + 1] = b; }
  __syncthreads();
  if (tid == 0) {
    sc[0] = sc[0] + sc[2] + sc[4] + sc[6];
    sc[1] = sc[1] + sc[3] + sc[5] + sc[7];
  }
  __syncthreads();
  a = sc[0]; b = sc[1];
  __syncthreads();
}

// reduce (a,b) over the first 256 threads of a 1024-thread block.
DEVI void red256_2(float& a, float& b, float* sc8) {
  int tid = threadIdx.x;
  #pragma unroll
  for (int m = 1; m < 64; m <<= 1) {
    a += __shfl_xor(a, m);
    b += __shfl_xor(b, m);
  }
  if (tid < 256 && (tid & 63) == 0) { sc8[(tid >> 6) * 2] = a; sc8[(tid >> 6) * 2 + 1] = b; }
  __syncthreads();
  a = sc8[0] + sc8[2] + sc8[4] + sc8[6];
  b = sc8[1] + sc8[3] + sc8[5] + sc8[7];
  __syncthreads();
}

// ---------------- weight transpose (f32 [k][n] -> bf16 [n][k]) + zero bstats ----
__global__ void kw_kernel(const float* w0, const float* w1, const float* w2, const float* w3,
                          ushort* wT, float* bstats) {
  int widx = blockIdx.y;
  const float* src = (widx == 0) ? w0 : (widx == 1) ? w1 : (widx == 2) ? w2 : w3;
  ushort* dst = wT + (size_t)widx * 65536;
  int tile = blockIdx.x;               // 0..15
  int k0 = (tile >> 2) * 64, n0 = (tile & 3) * 64;
  __shared__ float t[64][65];
  int tid = threadIdx.x;
  int r = tid >> 2, c0 = (tid & 3) * 16;
  #pragma unroll
  for (int j = 0; j < 16; j += 4) {
    float4 v = *reinterpret_cast<const float4*>(src + (size_t)(k0 + r) * 256 + n0 + c0 + j);
    t[r][c0 + j + 0] = v.x; t[r][c0 + j + 1] = v.y;
    t[r][c0 + j + 2] = v.z; t[r][c0 + j + 3] = v.w;
  }
  __syncthreads();
  ushort buf[16];
  #pragma unroll
  for (int j = 0; j < 16; j++) buf[j] = f2bf(t[c0 + j][r]);
  size_t o = (size_t)(n0 + r) * 256 + k0 + c0;
  *reinterpret_cast<uint4*>(dst + o) = *reinterpret_cast<uint4*>(&buf[0]);
  *reinterpret_cast<uint4*>(dst + o + 8) = *reinterpret_cast<uint4*>(&buf[8]);
  if (blockIdx.x == 0 && blockIdx.y == 0 && tid < 64) bstats[tid] = 0.f;
}

// ---------------- GRU/MLP/q weight prepack to bf16 ----------------------------
__global__ void kw2_kernel(const float* wih, const float* whh, const float* w1,
                           const float* w2, const float* qw,
                           ushort* grup, ushort* w1b, ushort* w2b, ushort* qwb) {
  int d = blockIdx.x, c = threadIdx.x;
  ushort p6[6];
  p6[0] = f2bf(wih[(size_t)d * 768 + c]);
  p6[1] = f2bf(wih[(size_t)d * 768 + 256 + c]);
  p6[2] = f2bf(wih[(size_t)d * 768 + 512 + c]);
  p6[3] = f2bf(whh[(size_t)d * 768 + c]);
  p6[4] = f2bf(whh[(size_t)d * 768 + 256 + c]);
  p6[5] = f2bf(whh[(size_t)d * 768 + 512 + c]);
  size_t o = ((size_t)d * 256 + c) * 6;
  *reinterpret_cast<uint3*>(grup + o) = *reinterpret_cast<uint3*>(p6);
  int i = d * 256 + c;
  w1b[i] = f2bf(w1[i]);
  w2b[i] = f2bf(w2[i]);
  qwb[i] = f2bf(qw[i]);
}

// ---------------- batch stats: sum, sumsq of h = x + pos over [D,NTOK] ---------
__global__ void k1_stats(const float* x, const float* pos_w, const float* pos_b, float* bstats) {
  int b = blockIdx.y, blk = blockIdx.x, tid = threadIdx.x;
  const float* xb = x + (size_t)b * 1048576;
  float s = 0.f, sq = 0.f;
  for (int i = 0; i < 16; i++) {
    int e4 = blk * 4096 + i * 256 + tid;   // float4 index within batch
    int e = e4 * 4;
    int d = e >> 12, t = e & 4095;
    int ii = t >> 6, j0 = t & 63;
    float xx = ii * (1.f / 63.f);
    float c0 = pos_w[512 + d] + pos_w[768 + d] + pos_b[d];
    float cx = pos_w[d] - pos_w[512 + d];
    float cy = pos_w[256 + d] - pos_w[768 + d];
    float4 v = reinterpret_cast<const float4*>(xb)[e4];
    float base = c0 + xx * cx;
    #pragma unroll
    for (int j = 0; j < 4; j++) {
      float yy = (j0 + j) * (1.f / 63.f);
      float h = (&v.x)[j] + base + yy * cy;
      s += h; sq += h * h;
    }
  }
  blk_reduce2(s, sq);
  if (tid == 0) {
    atomicAdd(&bstats[b * 2], s);
    atomicAdd(&bstats[b * 2 + 1], sq);
  }
}

// ---------------- fused encoder: tokens -> fm1 -> fm2+LN -> {k, v} --------------
// Per block: 128 token rows of one batch. Activation tile lives in swizzled LDS.
// B-operand fragments read directly from global (L2-resident 128 KB weights).
// LDS element (r, c) at byte r*512 + ((c*2) ^ ((r&7)<<4)).
__global__ __launch_bounds__(512) void enc_fused(
    const float* __restrict__ x, const float* __restrict__ pos_w,
    const float* __restrict__ pos_b, const float* __restrict__ enc_g,
    const float* __restrict__ enc_b, const float* __restrict__ bstats,
    const ushort* __restrict__ WT,
    const float* __restrict__ fb1, const float* __restrict__ fb2,
    const float* __restrict__ lng, const float* __restrict__ lnb,
    const float* __restrict__ kbias, const float* __restrict__ vbias,
    ushort* __restrict__ kout, ushort* __restrict__ vout) {
  extern __shared__ __align__(16) char smem[];            // 64KB bufT + 4KB rst
  float (*rst)[4][2] = reinterpret_cast<float (*)[4][2]>(smem + 65536);
  int rb = blockIdx.x, b = blockIdx.y;
  int tid = threadIdx.x;
  int t0 = rb * 128;

  // ---- tokens tile (x + pos, batch-LN, enc affine) -> bufT ----
  {
    float mean = bstats[b * 2] * (1.f / 1048576.f);
    float rstd = rsqrtf(bstats[b * 2 + 1] * (1.f / 1048576.f) - mean * mean + 1e-5f);
    int tl = tid & 127, dq = tid >> 7;
    int gt = t0 + tl;
    float px = (float)(gt >> 6) * (1.f / 63.f), py = (float)(gt & 63) * (1.f / 63.f);
    const float* xb = x + (size_t)b * 1048576 + gt;
    const float* eg = enc_g + (size_t)gt * 256;
    const float* eb = enc_b + (size_t)gt * 256;
    #pragma unroll
    for (int dp = 0; dp < 8; ++dp) {
      int d0 = dq * 64 + dp * 8;
      float4 g0 = *reinterpret_cast<const float4*>(eg + d0);
      float4 g1 = *reinterpret_cast<const float4*>(eg + d0 + 4);
      float4 e0 = *reinterpret_cast<const float4*>(eb + d0);
      float4 e1 = *reinterpret_cast<const float4*>(eb + d0 + 4);
      ushort o[8];
      #pragma unroll
      for (int e = 0; e < 8; ++e) {
        int d = d0 + e;
        float c0 = pos_w[512 + d] + pos_w[768 + d] + pos_b[d];
        float cx = pos_w[d] - pos_w[512 + d];
        float cy = pos_w[256 + d] - pos_w[768 + d];
        float h = xb[(size_t)d * 4096] + c0 + px * cx + py * cy;
        h = (h - mean) * rstd;
        float gg = (e < 4) ? (&g0.x)[e] : (&g1.x)[e - 4];
        float bb = (e < 4) ? (&e0.x)[e] : (&e1.x)[e - 4];
        o[e] = f2bf(h * gg + bb);
      }
      *reinterpret_cast<uint4*>(smem + tl * 512 + ((d0 * 2) ^ ((tl & 7) << 4))) =
          *reinterpret_cast<uint4*>(&o[0]);
    }
  }
  __syncthreads();

  int w = tid >> 6, lane = tid & 63;
  int wr = w >> 2, wc = w & 3;            // 2(M) x 4(N) waves, wave tile 64x64
  int l15 = lane & 15, g = lane >> 4;
  int col[4];
  #pragma unroll
  for (int n = 0; n < 4; n++) col[n] = wc * 64 + n * 16 + l15;

  f32x4 acc[4][4], acc2[4][4];

  // ======== G1: bufT = relu(bufT @ W1 + fb1) ========
  #pragma unroll
  for (int m = 0; m < 4; m++)
    #pragma unroll
    for (int n = 0; n < 4; n++) acc[m][n] = (f32x4)(0.f);
  #pragma unroll 2
  for (int ks = 0; ks < 8; ++ks) {
    int kb2 = ks * 64 + g * 16;           // byte offset of k within LDS row
    int ke = ks * 32 + g * 8;             // element k for B
    short8 af[4], bf[4];
    #pragma unroll
    for (int m = 0; m < 4; m++) {
      int r = wr * 64 + m * 16 + l15;
      af[m] = *reinterpret_cast<const short8*>(smem + r * 512 + (kb2 ^ ((r & 7) << 4)));
    }
    #pragma unroll
    for (int n = 0; n < 4; n++)
      bf[n] = *reinterpret_cast<const short8*>(WT + (size_t)col[n] * 256 + ke);
    #pragma unroll
    for (int m = 0; m < 4; m++)
      #pragma unroll
      for (int n = 0; n < 4; n++)
        acc[m][n] = __builtin_amdgcn_mfma_f32_16x16x32_bf16(af[m], bf[n], acc[m][n], 0, 0, 0);
  }
  __syncthreads();                        // all reads of bufT done
  #pragma unroll
  for (int n = 0; n < 4; n++) {
    float bv = fb1[col[n]];
    #pragma unroll
    for (int m = 0; m < 4; m++) {
      int rbse = wr * 64 + m * 16 + g * 4;
      #pragma unroll
      for (int q = 0; q < 4; q++) {
        int r = rbse + q;
        float v = fmaxf(acc[m][n][q] + bv, 0.f);
        *reinterpret_cast<ushort*>(smem + r * 512 + ((col[n] * 2) ^ ((r & 7) << 4))) = f2bf(v);
      }
    }
  }
  __syncthreads();

  // ======== G2: bufT = rowLN(relu(bufT @ W2 + fb2)) ========
  #pragma unroll
  for (int m = 0; m < 4; m++)
    #pragma unroll
    for (int n = 0; n < 4; n++) acc[m][n] = (f32x4)(0.f);
  {
    const ushort* WT2 = WT + 65536;
    #pragma unroll 2
    for (int ks = 0; ks < 8; ++ks) {
      int kb2 = ks * 64 + g * 16;
      int ke = ks * 32 + g * 8;
      short8 af[4], bf[4];
      #pragma unroll
      for (int m = 0; m < 4; m++) {
        int r = wr * 64 + m * 16 + l15;
        af[m] = *reinterpret_cast<const short8*>(smem + r * 512 + (kb2 ^ ((r & 7) << 4)));
      }
      #pragma unroll
      for (int n = 0; n < 4; n++)
        bf[n] = *reinterpret_cast<const short8*>(WT2 + (size_t)col[n] * 256 + ke);
      #pragma unroll
      for (int m = 0; m < 4; m++)
        #pragma unroll
        for (int n = 0; n < 4; n++)
          acc[m][n] = __builtin_amdgcn_mfma_f32_16x16x32_bf16(af[m], bf[n], acc[m][n], 0, 0, 0);
    }
  }
  // bias + relu, then row-LN partial stats
  #pragma unroll
  for (int n = 0; n < 4; n++) {
    float bv = fb2[col[n]];
    #pragma unroll
    for (int m = 0; m < 4; m++)
      #pragma unroll
      for (int q = 0; q < 4; q++)
        acc[m][n][q] = fmaxf(acc[m][n][q] + bv, 0.f);
  }
  #pragma unroll
  for (int m = 0; m < 4; m++)
    #pragma unroll
    for (int q = 0; q < 4; q++) {
      float rs = 0.f, rq = 0.f;
      #pragma unroll
      for (int n = 0; n < 4; n++) { float v = acc[m][n][q]; rs += v; rq += v * v; }
      #pragma unroll
      for (int msk = 1; msk < 16; msk <<= 1) { rs += __shfl_xor(rs, msk); rq += __shfl_xor(rq, msk); }
      if (l15 == 0) {
        int lr = wr * 64 + m * 16 + g * 4 + q;
        rst[lr][wc][0] = rs; rst[lr][wc][1] = rq;
      }
    }
  __syncthreads();                        // rst ready AND all bufT reads done
  {
    float gcol[4], ocol[4];
    #pragma unroll
    for (int n = 0; n < 4; n++) { gcol[n] = lng[col[n]]; ocol[n] = lnb[col[n]]; }
    #pragma unroll
    for (int m = 0; m < 4; m++)
      #pragma unroll
      for (int q = 0; q < 4; q++) {
        int lr = wr * 64 + m * 16 + g * 4 + q;
        float s = rst[lr][0][0] + rst[lr][1][0] + rst[lr][2][0] + rst[lr][3][0];
        float ssq = rst[lr][0][1] + rst[lr][1][1] + rst[lr][2][1] + rst[lr][3][1];
        float mean = s * (1.f / 256.f);
        float rstd = rsqrtf(ssq * (1.f / 256.f) - mean * mean + 1e-5f);
        #pragma unroll
        for (int n = 0; n < 4; n++) {
          float val = (acc[m][n][q] - mean) * rstd * gcol[n] + ocol[n];
          *reinterpret_cast<ushort*>(smem + lr * 512 + ((col[n] * 2) ^ ((lr & 7) << 4))) = f2bf(val);
        }
      }
  }
  __syncthreads();

  // ======== G3+G4: k = bufT @ Wk + kb; v = bufT @ Wv + vb ========
  #pragma unroll
  for (int m = 0; m < 4; m++)
    #pragma unroll
    for (int n = 0; n < 4; n++) { acc[m][n] = (f32x4)(0.f); acc2[m][n] = (f32x4)(0.f); }
  {
    const ushort* WTk = WT + 131072;
    const ushort* WTv = WT + 196608;
    #pragma unroll 2
    for (int ks = 0; ks < 8; ++ks) {
      int kb2 = ks * 64 + g * 16;
      int ke = ks * 32 + g * 8;
      short8 af[4], bfk[4], bfv[4];
      #pragma unroll
      for (int m = 0; m < 4; m++) {
        int r = wr * 64 + m * 16 + l15;
        af[m] = *reinterpret_cast<const short8*>(smem + r * 512 + (kb2 ^ ((r & 7) << 4)));
      }
      #pragma unroll
      for (int n = 0; n < 4; n++) {
        bfk[n] = *reinterpret_cast<const short8*>(WTk + (size_t)col[n] * 256 + ke);
        bfv[n] = *reinterpret_cast<const short8*>(WTv + (size_t)col[n] * 256 + ke);
      }
      #pragma unroll
      for (int m = 0; m < 4; m++)
        #pragma unroll
        for (int n = 0; n < 4; n++) {
          acc[m][n] = __builtin_amdgcn_mfma_f32_16x16x32_bf16(af[m], bfk[n], acc[m][n], 0, 0, 0);
          acc2[m][n] = __builtin_amdgcn_mfma_f32_16x16x32_bf16(af[m], bfv[n], acc2[m][n], 0, 0, 0);
        }
    }
  }
  size_t gbase = (size_t)(b * 4096 + t0);
  #pragma unroll
  for (int m = 0; m < 4; m++) {
    int rbse = wr * 64 + m * 16 + g * 4;
    #pragma unroll
    for (int n = 0; n < 4; n++) {
      float kbv = kbias[col[n]], vbv = vbias[col[n]];
      #pragma unroll
      for (int q = 0; q < 4; q++) {
        size_t o = (gbase + rbse + q) * 256 + col[n];
        kout[o] = f2bf(acc[m][n][q] + kbv);
        vout[o] = f2bf(acc2[m][n][q] + vbv);
      }
    }
  }
}

// ---------------- slot init + slot-LN + q projection (K-split, 1024 thr) --------
__global__ __launch_bounds__(1024) void kslots_q(const float* eps, const float* loc,
                                                 const float* lsc, const float* sg,
                                                 const float* sb, const ushort* qwb,
                                                 const float* qb, float* slots, ushort* qT,
                                                 float* upd, float* asum) {
  int s = blockIdx.x, b = blockIdx.y, tid = threadIdx.x;
  int c = tid & 255, kq = tid >> 8;
  size_t base = ((size_t)b * 8 + s) * 256;
  __shared__ float sn[256];
  __shared__ float red[4][256];
  __shared__ float sc8[8];
  float val = 0.f;
  if (tid < 256) {
    val = loc[c] + expf(lsc[c]) * eps[base + c];
    slots[base + c] = val;
    upd[base + c] = 0.f;
    qT[((size_t)b * 16 + 8 + s) * 256 + c] = 0;   // zero q padding row
    if (tid == 0) asum[b * 8 + s] = 0.f;
  }
  float aa = val, bb = val * val;
  red256_2(aa, bb, sc8);
  if (tid < 256) {
    float mean = aa * (1.f / 256.f);
    float rstd = rsqrtf(bb * (1.f / 256.f) - mean * mean + 1e-5f);
    sn[c] = (val - mean) * rstd * sg[c] + sb[c];
  }
  __syncthreads();
  float qm = 0.f;
  const ushort* qp = qwb + (size_t)(kq * 64) * 256 + c;
  #pragma unroll 8
  for (int d0 = 0; d0 < 64; d0++) qm = fmaf(sn[kq * 64 + d0], bf2f(qp[(size_t)d0 * 256]), qm);
  red[kq][c] = qm;
  __syncthreads();
  if (tid < 256) {
    float qacc = qb[c] + red[0][c] + red[1][c] + red[2][c] + red[3][c];
    qT[((size_t)b * 16 + s) * 256 + c] = f2bf(qacc * 0.0625f);   // fold SCALE
  }
}

// ---------------- fused attention: dots(MFMA) + slot-softmax + attn@v -----------
__global__ __launch_bounds__(256) void kbc_kernel(const ushort* __restrict__ kmat,
                                                  const ushort* __restrict__ vmat,
                                                  const ushort* __restrict__ qT,
                                                  float* __restrict__ attn_sum,
                                                  float* __restrict__ upd) {
  int tcx = blockIdx.x;               // 0..15 (256 tokens each)
  int b = blockIdx.y;
  int tid = threadIdx.x, w = tid >> 6, lane = tid & 63;
  __shared__ __align__(16) ushort Ks[256 * 64];   // K staging (swizzled); reused as red
  __shared__ float at[256][9];                    // attn [token][slot], +1 pad
  __shared__ float wsum[4][16];
  const ushort* kbase = kmat + ((size_t)b * 4096 + tcx * 256) * 256;
  const ushort* qbase = qT + (size_t)b * 16 * 256;
  f32x4 acc[4];
  #pragma unroll
  for (int m = 0; m < 4; m++) acc[m] = (f32x4)(0.f);
  for (int ks = 0; ks < 4; ks++) {
    int k0 = ks * 64;
    __syncthreads();
    #pragma unroll
    for (int i = 0; i < 8; i++) {
      int idx = tid + i * 256;
      int r = idx >> 3, cc = idx & 7;
      // pre-swizzled source so that linear LDS dest == swizzled layout
      gload16(kbase + (size_t)r * 256 + k0 + (cc ^ (r & 7)) * 8, &Ks[idx * 8]);
    }
    __syncthreads();
    #pragma unroll
    for (int ksub = 0; ksub < 2; ksub++) {
      int kk = ksub * 32 + (lane >> 4) * 8;
      short8 bq = *reinterpret_cast<const short8*>(qbase + (lane & 15) * 256 + k0 + kk);
      #pragma unroll
      for (int m = 0; m < 4; m++) {
        int r = w * 64 + m * 16 + (lane & 15);
        short8 af = *reinterpret_cast<const short8*>(
            reinterpret_cast<const char*>(Ks) + r * 128 + ((kk * 2) ^ ((r & 7) << 4)));
        acc[m] = __builtin_amdgcn_mfma_f32_16x16x32_bf16(af, bq, acc[m], 0, 0, 0);
      }
    }
  }
  bool valid = (lane & 15) < 8;
  float lsum = 0.f;
  int srow = (lane >> 4) * 4;
  #pragma unroll
  for (int m = 0; m < 4; m++) {
    #pragma unroll
    for (int q = 0; q < 4; q++) {
      float d = acc[m][q];
      float mv = valid ? d : -1e30f;
      #pragma unroll
      for (int msk = 1; msk < 16; msk <<= 1) mv = fmaxf(mv, __shfl_xor(mv, msk));
      float e = valid ? expf(d - mv) : 0.f;
      float ssum = e;
      #pragma unroll
      for (int msk = 1; msk < 16; msk <<= 1) ssum += __shfl_xor(ssum, msk);
      if (valid) {
        float av = e / ssum + 1e-8f;
        int t = w * 64 + m * 16 + srow + q;
        at[t][lane & 15] = av;
        lsum += av;
      }
    }
  }
  lsum += __shfl_xor(lsum, 16);
  lsum += __shfl_xor(lsum, 32);
  if (lane < 16) wsum[w][lane] = lsum;
  __syncthreads();                     // at[] complete; Ks reads done -> reuse as red
  if (tid < 8) {
    float tot = wsum[0][tid] + wsum[1][tid] + wsum[2][tid] + wsum[3][tid];
    atomicAdd(&attn_sum[b * 8 + tid], tot);
  }
  float pacc[8][4];
  #pragma unroll
  for (int s = 0; s < 8; s++)
    #pragma unroll
    for (int j = 0; j < 4; j++) pacc[s][j] = 0.f;
  const ushort* vb = vmat + ((size_t)b * 4096 + tcx * 256) * 256;
  for (int ti = 0; ti < 64; ti++) {
    int t = w * 64 + ti;
    uint2 vv = *reinterpret_cast<const uint2*>(vb + (size_t)t * 256 + lane * 4);
    ushort us[4]; *reinterpret_cast<uint2*>(us) = vv;
    float vf[4];
    #pragma unroll
    for (int j = 0; j < 4; j++) vf[j] = bf2f(us[j]);
    #pragma unroll
    for (int s = 0; s < 8; s++) {
      float a = at[t][s];
      #pragma unroll
      for (int j = 0; j < 4; j++) pacc[s][j] = fmaf(a, vf[j], pacc[s][j]);
    }
  }
  float (*red)[8][256] = reinterpret_cast<float (*)[8][256]>(Ks);  // 32 KB overlay
  #pragma unroll
  for (int s = 0; s < 8; s++) {
    float4 v4; v4.x = pacc[s][0]; v4.y = pacc[s][1]; v4.z = pacc[s][2]; v4.w = pacc[s][3];
    *reinterpret_cast<float4*>(&red[w][s][lane * 4]) = v4;
  }
  __syncthreads();
  #pragma unroll
  for (int i = 0; i < 8; i++) {
    int idx = tid + i * 256;
    int s = idx >> 8, d = idx & 255;
    float sum = red[0][s][d] + red[1][s][d] + red[2][s][d] + red[3][s][d];
    atomicAdd(&upd[((size_t)b * 8 + s) * 256 + d], sum);
  }
}

// ---------------- GRU + residual MLP + next-iter q (K-split, 1024 thr) ---------
__global__ __launch_bounds__(1024) void kd_kernel(
    const float* __restrict__ upd_in, const float* __restrict__ attn_sum,
    float* __restrict__ slots, const ushort* __restrict__ grup,
    const float* __restrict__ bih, const float* __restrict__ bhh,
    const float* __restrict__ pre_g, const float* __restrict__ pre_b,
    const ushort* __restrict__ w1b, const float* __restrict__ b1,
    const ushort* __restrict__ w2b, const float* __restrict__ b2,
    const float* __restrict__ sg, const float* __restrict__ sb,
    const ushort* __restrict__ qwb, const float* __restrict__ qb,
    ushort* __restrict__ qT_next, float* __restrict__ upd_clear,
    float* __restrict__ asum_clear, float* __restrict__ out_final) {
  int s = blockIdx.x, b = blockIdx.y;
  int tid = threadIdx.x, c = tid & 255, kq = tid >> 8;
  size_t base = ((size_t)b * 8 + s) * 256;
  __shared__ float u[256], p[256], fbuf[256];
  __shared__ float red6[6][4][256];
  __shared__ float sc8[8];
  if (tid < 256) {
    u[c] = upd_in[base + c] * (1.f / attn_sum[b * 8 + s]);
    p[c] = slots[base + c];
  }
  __syncthreads();
  float a0 = 0.f, a1 = 0.f, a2 = 0.f, a3 = 0.f, a4 = 0.f, a5 = 0.f;
  const ushort* gp = grup + ((size_t)(kq * 64) * 256 + c) * 6;
  #pragma unroll 4
  for (int d0 = 0; d0 < 64; d0++) {
    int d = kq * 64 + d0;
    uint3 w3 = *reinterpret_cast<const uint3*>(gp + (size_t)d0 * 1536);
    float ud = u[d], pd = p[d];
    a0 = fmaf(ud, bf2f((ushort)(w3.x & 0xffff)), a0);
    a1 = fmaf(ud, bf2f((ushort)(w3.x >> 16)), a1);
    a2 = fmaf(ud, bf2f((ushort)(w3.y & 0xffff)), a2);
    a3 = fmaf(pd, bf2f((ushort)(w3.y >> 16)), a3);
    a4 = fmaf(pd, bf2f((ushort)(w3.z & 0xffff)), a4);
    a5 = fmaf(pd, bf2f((ushort)(w3.z >> 16)), a5);
  }
  red6[0][kq][c] = a0; red6[1][kq][c] = a1; red6[2][kq][c] = a2;
  red6[3][kq][c] = a3; red6[4][kq][c] = a4; red6[5][kq][c] = a5;
  __syncthreads();
  float hv = 0.f;
  if (tid < 256) {
    float gi0 = bih[c], gi1 = bih[256 + c], gi2 = bih[512 + c];
    float gh0 = bhh[c], gh1 = bhh[256 + c], gh2 = bhh[512 + c];
    #pragma unroll
    for (int k2 = 0; k2 < 4; k2++) {
      gi0 += red6[0][k2][c]; gi1 += red6[1][k2][c]; gi2 += red6[2][k2][c];
      gh0 += red6[3][k2][c]; gh1 += red6[4][k2][c]; gh2 += red6[5][k2][c];
    }
    float r = 1.f / (1.f + expf(-(gi0 + gh0)));
    float z = 1.f / (1.f + expf(-(gi1 + gh1)));
    float n = tanhf(gi2 + r * gh2);
    hv = (1.f - z) * n + z * p[c];
  }
  float aa = hv, bb = hv * hv;
  red256_2(aa, bb, sc8);
  if (tid < 256) {
    float mean = aa * (1.f / 256.f);
    float rstd = rsqrtf(bb * (1.f / 256.f) - mean * mean + 1e-5f);
    fbuf[c] = (hv - mean) * rstd * pre_g[c] + pre_b[c];
  }
  __syncthreads();
  float m1 = 0.f;
  const ushort* w1p = w1b + (size_t)(kq * 64) * 256 + c;
  #pragma unroll 8
  for (int d0 = 0; d0 < 64; d0++) m1 = fmaf(fbuf[kq * 64 + d0], bf2f(w1p[(size_t)d0 * 256]), m1);
  red6[0][kq][c] = m1;
  __syncthreads();
  if (tid < 256) {
    float acc1 = b1[c] + red6[0][0][c] + red6[0][1][c] + red6[0][2][c] + red6[0][3][c];
    fbuf[c] = fmaxf(acc1, 0.f);
  }
  __syncthreads();
  float m2 = 0.f;
  const ushort* w2p = w2b + (size_t)(kq * 64) * 256 + c;
  #pragma unroll 8
  for (int d0 = 0; d0 < 64; d0++) m2 = fmaf(fbuf[kq * 64 + d0], bf2f(w2p[(size_t)d0 * 256]), m2);
  red6[1][kq][c] = m2;
  __syncthreads();
  float res = 0.f;
  if (tid < 256) {
    float acc2 = b2[c] + red6[1][0][c] + red6[1][1][c] + red6[1][2][c] + red6[1][3][c];
    res = hv + fmaxf(acc2, 0.f);
    slots[base + c] = res;
    if (qT_next == nullptr) out_final[base + c] = res;
  }
  if (qT_next != nullptr) {
    float a2s = res, b2s = res * res;
    red256_2(a2s, b2s, sc8);
    if (tid < 256) {
      float mean2 = a2s * (1.f / 256.f);
      float rstd2 = rsqrtf(b2s * (1.f / 256.f) - mean2 * mean2 + 1e-5f);
      fbuf[c] = (res - mean2) * rstd2 * sg[c] + sb[c];
    }
    __syncthreads();
    float qm = 0.f;
    const ushort* qp = qwb + (size_t)(kq * 64) * 256 + c;
    #pragma unroll 8
    for (int d0 = 0; d0 < 64; d0++) qm = fmaf(fbuf[kq * 64 + d0], bf2f(qp[(size_t)d0 * 256]), qm);
    red6[2][kq][c] = qm;
    __syncthreads();
    if (tid < 256) {
      float qacc = qb[c] + red6[2][0][c] + red6[2][1][c] + red6[2][2][c] + red6[2][3][c];
      qT_next[((size_t)b * 16 + s) * 256 + c] = f2bf(qacc * 0.0625f);
      upd_clear[base + c] = 0.f;
      if (tid == 0) asum_clear[b * 8 + s] = 0.f;
    }
  }
}

extern "C" void kernel_launch(void* const* d_in, const int* in_sizes, int n_in,
                              void* d_out, int out_size, void* d_ws, size_t ws_size,
                              hipStream_t stream) {
  const float* x         = (const float*)d_in[0];
  const float* eps_noise = (const float*)d_in[1];
  const float* pos_w     = (const float*)d_in[2];
  const float* pos_b     = (const float*)d_in[3];
  const float* enc_g     = (const float*)d_in[4];
  const float* enc_b     = (const float*)d_in[5];
  const float* fm_w1     = (const float*)d_in[6];
  const float* fm_b1     = (const float*)d_in[7];
  const float* fm_w2     = (const float*)d_in[8];
  const float* fm_b2     = (const float*)d_in[9];
  const float* in_g      = (const float*)d_in[10];
  const float* in_b      = (const float*)d_in[11];
  const float* q_w       = (const float*)d_in[12];
  const float* q_b       = (const float*)d_in[13];
  const float* k_w       = (const float*)d_in[14];
  const float* k_b       = (const float*)d_in[15];
  const float* v_w       = (const float*)d_in[16];
  const float* v_b       = (const float*)d_in[17];
  const float* gru_wih   = (const float*)d_in[18];
  const float* gru_whh   = (const float*)d_in[19];
  const float* gru_bih   = (const float*)d_in[20];
  const float* gru_bhh   = (const float*)d_in[21];
  const float* pre_g     = (const float*)d_in[22];
  const float* pre_b     = (const float*)d_in[23];
  const float* st_w1     = (const float*)d_in[24];
  const float* st_b1     = (const float*)d_in[25];
  const float* st_w2     = (const float*)d_in[26];
  const float* st_b2     = (const float*)d_in[27];
  const float* slot_g    = (const float*)d_in[28];
  const float* slot_b    = (const float*)d_in[29];
  const float* slots_loc = (const float*)d_in[30];
  const float* slots_lsc = (const float*)d_in[31];
  (void)in_sizes; (void)n_in; (void)out_size;

  char* ws = (char*)d_ws;
  const size_t OFF_BUFB   = 67108864;                 // bufA (v) at 0, bufB (k) here
  const size_t OFF_WT     = 134217728;                // 512 KB
  const size_t OFF_QT     = OFF_WT + 524288;          // 256 KB
  const size_t OFF_SLOTS  = OFF_QT + 262144;          // 256 KB
  const size_t OFF_UPD    = OFF_SLOTS + 262144;       // 256 KB
  const size_t OFF_BSTATS = OFF_UPD + 262144;         // 256 B
  const size_t OFF_ASUM   = OFF_BSTATS + 256;         // 1 KB
  const size_t OFF_GRUP   = OFF_ASUM + 1024;          // 768 KB
  const size_t OFF_W1B    = OFF_GRUP + 786432;        // 128 KB
  const size_t OFF_W2B    = OFF_W1B + 131072;         // 128 KB
  const size_t OFF_QWB    = OFF_W2B + 131072;         // 128 KB
  const size_t NEED       = OFF_QWB + 131072;
  if (ws_size < NEED) return;

  ushort* bufA   = (ushort*)ws;                       // v
  ushort* bufB   = (ushort*)(ws + OFF_BUFB);          // k
  ushort* wT     = (ushort*)(ws + OFF_WT);
  ushort* qT     = (ushort*)(ws + OFF_QT);
  float* slots   = (float*)(ws + OFF_SLOTS);
  float* upd     = (float*)(ws + OFF_UPD);
  float* bstats  = (float*)(ws + OFF_BSTATS);
  float* asum    = (float*)(ws + OFF_ASUM);
  ushort* grup   = (ushort*)(ws + OFF_GRUP);
  ushort* w1b    = (ushort*)(ws + OFF_W1B);
  ushort* w2b    = (ushort*)(ws + OFF_W2B);
  ushort* qwb    = (ushort*)(ws + OFF_QWB);

  hipFuncSetAttribute(reinterpret_cast<const void*>(enc_fused),
                      hipFuncAttributeMaxDynamicSharedMemorySize, 69632);

  kw_kernel<<<dim3(16, 4), 256, 0, stream>>>(fm_w1, fm_w2, k_w, v_w, wT, bstats);
  kw2_kernel<<<256, 256, 0, stream>>>(gru_wih, gru_whh, st_w1, st_w2, q_w,
                                      grup, w1b, w2b, qwb);
  k1_stats<<<dim3(64, 32), 256, 0, stream>>>(x, pos_w, pos_b, bstats);
  kslots_q<<<dim3(8, 32), 1024, 0, stream>>>(eps_noise, slots_loc, slots_lsc, slot_g, slot_b,
                                             qwb, q_b, slots, qT, upd, asum);
  enc_fused<<<dim3(32, 32), 512, 69632, stream>>>(
      x, pos_w, pos_b, enc_g, enc_b, bstats, wT,
      fm_b1, fm_b2, in_g, in_b, k_b, v_b, bufB, bufA);
  for (int it = 0; it < 3; it++) {
    kbc_kernel<<<dim3(16, 32), 256, 0, stream>>>(bufB, bufA, qT, asum, upd);
    bool last = (it == 2);
    kd_kernel<<<dim3(8, 32), 1024, 0, stream>>>(upd, asum, slots, grup,
        gru_bih, gru_bhh, pre_g, pre_b, w1b, st_b1, w2b, st_b2,
        slot_g, slot_b, qwb, q_b,
        last ? nullptr : qT, upd, asum, last ? (float*)d_out : nullptr);
  }
}